// Round 12
// baseline (159.236 us; speedup 1.0000x reference)
//
#include <hip/hip_runtime.h>
#include <hip/hip_bf16.h>
#include <stdint.h>
#include <stddef.h>

typedef __attribute__((ext_vector_type(8))) short bf16x8;
typedef __attribute__((ext_vector_type(4))) float f32x4;

#define NROWS 400000
#define KC 128
#define DIMS 64
#define NTILES (NROWS / 16)

__device__ __forceinline__ float frcp(float x) { return __builtin_amdgcn_rcpf(x); }

// pack 2 f32 -> 2 bf16 (RNE) in one u32; compiler emits v_cvt_pk_bf16_f32
__device__ __forceinline__ uint32_t pkbf(float lo, float hi) {
    union { __hip_bfloat162 h; uint32_t u; } v;
    v.h = __float22bfloat162_rn(make_float2(lo, hi));
    return v.u;
}
__device__ __forceinline__ bf16x8 pack8(f32x4 c0, f32x4 c1) {
    union { bf16x8 v; uint32_t u[4]; } r;
    r.u[0] = pkbf(c0[0], c0[1]);
    r.u[1] = pkbf(c0[2], c0[3]);
    r.u[2] = pkbf(c1[0], c1[1]);
    r.u[3] = pkbf(c1[2], c1[3]);
    return r.v;
}

// volatile LDS reads: cannot be hoisted out of the loop (keeps VGPR low),
// but do NOT order other memory ops (unlike an asm memory clobber).
__device__ __forceinline__ bf16x8 ldsv8(const bf16x8* p) {
    return *(const volatile bf16x8*)p;
}
__device__ __forceinline__ f32x4 ldsv4(const float* p) {
    return *(const volatile f32x4*)p;
}

// Stage -2*centers bf16 A-fragments into LDS + center norms into cnLDS.
__device__ __forceinline__ void stage_centers_T(
        const float* __restrict__ centers, bf16x8 (*blds)[2][64],
        float* cnLDS, int wid, int lane, int m, int g)
{
    #pragma unroll
    for (int cb = 0; cb < 8; ++cb) {
        float cacc = 0.f;
        bf16x8 bfr[2];
        #pragma unroll
        for (int h = 0; h < 2; ++h) {
            const float* src = centers + (size_t)(cb * 16 + m) * DIMS + h * 32 + g * 8;
            f32x4 c0 = *(const f32x4*)src;
            f32x4 c1 = *(const f32x4*)(src + 4);
            f32x4 s0, s1;
            #pragma unroll
            for (int j = 0; j < 4; ++j) {
                cacc += c0[j] * c0[j] + c1[j] * c1[j];
                s0[j] = -2.0f * c0[j];
                s1[j] = -2.0f * c1[j];
            }
            bfr[h] = pack8(s0, s1);
        }
        cacc += __shfl_xor(cacc, 16);
        cacc += __shfl_xor(cacc, 32);
        if (wid == 0) {
            blds[cb][0][lane] = bfr[0];
            blds[cb][1][lane] = bfr[1];
            if (g == 0) cnLDS[cb * 16 + m] = cacc;
        }
    }
    __syncthreads();
}

// K1: colsum of q. Tables stay in LDS via volatile reads -> low VGPR.
__global__ __launch_bounds__(256) void k1_colsum(
        const float* __restrict__ embeds, const float* __restrict__ centers,
        float* __restrict__ colsum_part, int nblocks)
{
    __shared__ bf16x8 blds[8][2][64];
    __shared__ float cnLDS[128];
    __shared__ float cl[4 * 128];
    const int tid = threadIdx.x, wid = tid >> 6, lane = tid & 63;
    const int m = lane & 15, g = lane >> 4;

    stage_centers_T(centers, blds, cnLDS, wid, lane, m, g);

    float csum[8][4];
    #pragma unroll
    for (int cb = 0; cb < 8; ++cb)
        #pragma unroll
        for (int r = 0; r < 4; ++r) csum[cb][r] = 0.f;

    const int gwid = blockIdx.x * 4 + wid;
    const int nw = nblocks * 4;

    int t = gwid;
    f32x4 n0, n1, n2, n3;
    if (t < NTILES) {
        const float* src = embeds + (size_t)(t * 16 + m) * DIMS + g * 8;
        n0 = *(const f32x4*)src;       n1 = *(const f32x4*)(src + 4);
        n2 = *(const f32x4*)(src + 32); n3 = *(const f32x4*)(src + 36);
    }
    for (; t < NTILES; t += nw) {
        f32x4 c0 = n0, c1 = n1, c2 = n2, c3 = n3;
        int tn = t + nw;
        if (tn < NTILES) {
            const float* src = embeds + (size_t)(tn * 16 + m) * DIMS + g * 8;
            n0 = *(const f32x4*)src;       n1 = *(const f32x4*)(src + 4);
            n2 = *(const f32x4*)(src + 32); n3 = *(const f32x4*)(src + 36);
        }
        float en = 0.f;
        #pragma unroll
        for (int j = 0; j < 4; ++j)
            en += c0[j] * c0[j] + c1[j] * c1[j] + c2[j] * c2[j] + c3[j] * c3[j];
        bf16x8 a0 = pack8(c0, c1);
        bf16x8 a1 = pack8(c2, c3);
        en += __shfl_xor(en, 16);
        en += __shfl_xor(en, 32);

        f32x4 acc[8];
        #pragma unroll
        for (int cb = 0; cb < 8; ++cb) {
            f32x4 a = {en, en, en, en};          // C = |e|^2; |c|^2 added after
            a = __builtin_amdgcn_mfma_f32_16x16x32_bf16(ldsv8(&blds[cb][0][lane]), a0, a, 0, 0, 0);
            a = __builtin_amdgcn_mfma_f32_16x16x32_bf16(ldsv8(&blds[cb][1][lane]), a1, a, 0, 0, 0);
            acc[cb] = a;
        }

        float rsp = 0.f;
        #pragma unroll
        for (int cb = 0; cb < 8; ++cb) {
            f32x4 cn4 = ldsv4(&cnLDS[cb * 16 + g * 4]);
            #pragma unroll
            for (int r = 0; r < 4; ++r) {
                float sq = fmaxf(acc[cb][r] + cn4[r], 0.f);
                float dist = frcp(1.0f + sq);
                acc[cb][r] = dist;
                rsp += dist;
            }
        }
        rsp += __shfl_xor(rsp, 16);
        rsp += __shfl_xor(rsp, 32);
        float invR = frcp(rsp);

        #pragma unroll
        for (int cb = 0; cb < 8; ++cb)
            #pragma unroll
            for (int r = 0; r < 4; ++r) csum[cb][r] += acc[cb][r] * invR;
    }

    #pragma unroll
    for (int cb = 0; cb < 8; ++cb)
        #pragma unroll
        for (int r = 0; r < 4; ++r) {
            float v = csum[cb][r];
            v += __shfl_xor(v, 1); v += __shfl_xor(v, 2);
            v += __shfl_xor(v, 4); v += __shfl_xor(v, 8);
            csum[cb][r] = v;
        }
    if (m == 0) {
        #pragma unroll
        for (int cb = 0; cb < 8; ++cb) {
            f32x4 v = {csum[cb][0], csum[cb][1], csum[cb][2], csum[cb][3]};
            *(f32x4*)&cl[wid * 128 + cb * 16 + g * 4] = v;
        }
    }
    __syncthreads();
    if (tid < 128) {
        float s = cl[tid] + cl[128 + tid] + cl[256 + tid] + cl[384 + tid];
        colsum_part[(size_t)tid * nblocks + blockIdx.x] = s;
    }
}

// K1b: 128 blocks, block k reduces contiguous row k -> invS[k], log2S[k]
__global__ __launch_bounds__(256) void k1b_reduce(
        const float* __restrict__ part, float* __restrict__ invS,
        float* __restrict__ lS, int nb)
{
    __shared__ float lds[4];
    const int k = blockIdx.x;
    const int tid = threadIdx.x, wid = tid >> 6, lane = tid & 63;
    float s = 0.f;
    for (int b = tid; b < nb; b += 256) s += part[(size_t)k * nb + b];
    s += __shfl_xor(s, 1);  s += __shfl_xor(s, 2);  s += __shfl_xor(s, 4);
    s += __shfl_xor(s, 8);  s += __shfl_xor(s, 16); s += __shfl_xor(s, 32);
    if (lane == 0) lds[wid] = s;
    __syncthreads();
    if (tid == 0) {
        float tot = lds[0] + lds[1] + lds[2] + lds[3];
        invS[k] = 1.0f / tot;
        lS[k] = __log2f(tot);
    }
}

// K2: recompute sq via transposed MFMA, write q, fused loss (log2 domain).
// Tables in LDS via volatile reads -> low VGPR; grid 768 = robust residency.
__global__ __launch_bounds__(256) void k2_q_loss(
        const float* __restrict__ embeds, const float* __restrict__ centers,
        const float* __restrict__ invS, const float* __restrict__ lS,
        float* __restrict__ q, float* __restrict__ losspart, int nblocks)
{
    __shared__ bf16x8 blds[8][2][64];
    __shared__ float cnLDS[128], isLDS[128], lsLDS[128];
    __shared__ float lds4[4];
    const int tid = threadIdx.x, wid = tid >> 6, lane = tid & 63;
    const int m = lane & 15, g = lane >> 4;

    if (tid < 128) { isLDS[tid] = invS[tid]; lsLDS[tid] = lS[tid]; }
    stage_centers_T(centers, blds, cnLDS, wid, lane, m, g);  // has __syncthreads

    float loss = 0.f;
    const int gwid = blockIdx.x * 4 + wid;
    const int nw = nblocks * 4;

    int t = gwid;
    f32x4 n0, n1, n2, n3;
    if (t < NTILES) {
        const float* src = embeds + (size_t)(t * 16 + m) * DIMS + g * 8;
        n0 = *(const f32x4*)src;       n1 = *(const f32x4*)(src + 4);
        n2 = *(const f32x4*)(src + 32); n3 = *(const f32x4*)(src + 36);
    }
    for (; t < NTILES; t += nw) {
        f32x4 c0 = n0, c1 = n1, c2 = n2, c3 = n3;
        int tn = t + nw;
        if (tn < NTILES) {
            const float* src = embeds + (size_t)(tn * 16 + m) * DIMS + g * 8;
            n0 = *(const f32x4*)src;       n1 = *(const f32x4*)(src + 4);
            n2 = *(const f32x4*)(src + 32); n3 = *(const f32x4*)(src + 36);
        }
        float en = 0.f;
        #pragma unroll
        for (int j = 0; j < 4; ++j)
            en += c0[j] * c0[j] + c1[j] * c1[j] + c2[j] * c2[j] + c3[j] * c3[j];
        bf16x8 a0 = pack8(c0, c1);
        bf16x8 a1 = pack8(c2, c3);
        en += __shfl_xor(en, 16);
        en += __shfl_xor(en, 32);

        f32x4 acc[8];
        #pragma unroll
        for (int cb = 0; cb < 8; ++cb) {
            f32x4 a = {en, en, en, en};
            a = __builtin_amdgcn_mfma_f32_16x16x32_bf16(ldsv8(&blds[cb][0][lane]), a0, a, 0, 0, 0);
            a = __builtin_amdgcn_mfma_f32_16x16x32_bf16(ldsv8(&blds[cb][1][lane]), a1, a, 0, 0, 0);
            acc[cb] = a;
        }

        float rsp = 0.f;
        #pragma unroll
        for (int cb = 0; cb < 8; ++cb) {
            f32x4 cn4 = ldsv4(&cnLDS[cb * 16 + g * 4]);
            #pragma unroll
            for (int r = 0; r < 4; ++r) {
                float sq = fmaxf(acc[cb][r] + cn4[r], 0.f);
                float dist = frcp(1.0f + sq);
                acc[cb][r] = dist;
                rsp += dist;
            }
        }
        rsp += __shfl_xor(rsp, 16);
        rsp += __shfl_xor(rsp, 32);
        float invR = frcp(rsp);

        float Wp = 0.f;
        float* qrow = q + (size_t)(t * 16 + m) * KC + g * 4;
        #pragma unroll
        for (int cb = 0; cb < 8; ++cb) {
            f32x4 is4 = ldsv4(&isLDS[cb * 16 + g * 4]);
            #pragma unroll
            for (int r = 0; r < 4; ++r) {
                float qv = acc[cb][r] * invR;
                acc[cb][r] = qv;
                qrow[cb * 16 + r] = qv;
                Wp += qv * qv * is4[r];
            }
        }
        Wp += __shfl_xor(Wp, 16);
        Wp += __shfl_xor(Wp, 32);
        float iw = frcp(Wp);
        float lw = __log2f(Wp);

        #pragma unroll
        for (int cb = 0; cb < 8; ++cb) {
            f32x4 is4 = ldsv4(&isLDS[cb * 16 + g * 4]);
            f32x4 ls4 = ldsv4(&lsLDS[cb * 16 + g * 4]);
            #pragma unroll
            for (int r = 0; r < 4; ++r) {
                float qv = acc[cb][r];
                float w = qv * qv * is4[r];
                loss += w * iw * (__log2f(qv) - ls4[r] - lw);
            }
        }
    }

    loss += __shfl_xor(loss, 1);  loss += __shfl_xor(loss, 2);
    loss += __shfl_xor(loss, 4);  loss += __shfl_xor(loss, 8);
    loss += __shfl_xor(loss, 16); loss += __shfl_xor(loss, 32);
    if (lane == 0) lds4[wid] = loss;
    __syncthreads();
    if (tid == 0) losspart[blockIdx.x] = lds4[0] + lds4[1] + lds4[2] + lds4[3];
}

// K2b: final loss reduce; convert log2 -> ln
__global__ __launch_bounds__(1024) void k2b_final(
        const float* __restrict__ losspart, int nb, float* __restrict__ out)
{
    __shared__ float lds[16];
    const int tid = threadIdx.x;
    float s = 0.f;
    for (int b = tid; b < nb; b += 1024) s += losspart[b];
    s += __shfl_xor(s, 1);  s += __shfl_xor(s, 2);  s += __shfl_xor(s, 4);
    s += __shfl_xor(s, 8);  s += __shfl_xor(s, 16); s += __shfl_xor(s, 32);
    if ((tid & 63) == 0) lds[tid >> 6] = s;
    __syncthreads();
    if (tid == 0) {
        float tot = 0.f;
        #pragma unroll
        for (int i = 0; i < 16; ++i) tot += lds[i];
        out[0] = (float)((double)tot * 0.6931471805599453 /
                         (double)((size_t)NROWS * KC));
    }
}

extern "C" void kernel_launch(void* const* d_in, const int* in_sizes, int n_in,
                              void* d_out, int out_size, void* d_ws, size_t ws_size,
                              hipStream_t stream)
{
    const float* embeds  = (const float*)d_in[0];
    const float* centers = (const float*)d_in[1];
    float* out  = (float*)d_out;
    float* qbuf = out + 1;
    float* ws   = (float*)d_ws;

    const int GB1 = 768, GB2 = 768;   // 3 blocks/CU: robust residency bet, no bounds
    float* colsum_part = ws;                          // 128 * GB1 (transposed)
    float* invS  = ws + (size_t)GB1 * 128;            // 128
    float* lS    = invS + 128;                        // 128
    float* lpart = lS + 128;                          // GB2

    hipLaunchKernelGGL(k1_colsum, dim3(GB1), dim3(256), 0, stream,
                       embeds, centers, colsum_part, GB1);
    hipLaunchKernelGGL(k1b_reduce, dim3(128), dim3(256), 0, stream,
                       colsum_part, invS, lS, GB1);
    hipLaunchKernelGGL(k2_q_loss, dim3(GB2), dim3(256), 0, stream,
                       embeds, centers, invS, lS, qbuf, lpart, GB2);
    hipLaunchKernelGGL(k2b_final, dim3(1), dim3(1024), 0, stream,
                       lpart, GB2, out);
}

// Round 13
// 113.356 us; speedup vs baseline: 1.4047x; 1.4047x over previous
//
#include <hip/hip_runtime.h>
#include <hip/hip_bf16.h>
#include <stdint.h>
#include <stddef.h>

typedef __attribute__((ext_vector_type(8))) short bf16x8;
typedef __attribute__((ext_vector_type(4))) float f32x4;

#define NROWS 400000
#define KC 128
#define DIMS 64
#define NTILES (NROWS / 16)

__device__ __forceinline__ float frcp(float x) { return __builtin_amdgcn_rcpf(x); }

// opaque zero in an SGPR: asm volatile -> re-materialized every iteration, so
// LDS table reads indexed with +zr are loop-variant (not hoistable into VGPRs),
// yet remain NORMAL loads (reorderable; no volatile chain, no memory clobber).
__device__ __forceinline__ int opaque_zero() {
    int zr;
    asm volatile("s_mov_b32 %0, 0" : "=s"(zr));
    return zr;
}

// pack 2 f32 -> 2 bf16 (RNE); compiler emits v_cvt_pk_bf16_f32
__device__ __forceinline__ uint32_t pkbf(float lo, float hi) {
    union { __hip_bfloat162 h; uint32_t u; } v;
    v.h = __float22bfloat162_rn(make_float2(lo, hi));
    return v.u;
}
__device__ __forceinline__ bf16x8 pack8(f32x4 c0, f32x4 c1) {
    union { bf16x8 v; uint32_t u[4]; } r;
    r.u[0] = pkbf(c0[0], c0[1]);
    r.u[1] = pkbf(c0[2], c0[3]);
    r.u[2] = pkbf(c1[0], c1[1]);
    r.u[3] = pkbf(c1[2], c1[3]);
    return r.v;
}

// Stage -2*centers bf16 A-fragments into LDS + center norms (f32x4-typed LDS).
__device__ __forceinline__ void stage_centers_T(
        const float* __restrict__ centers, bf16x8 (*blds)[2][64],
        f32x4* cnLDS4, int wid, int lane, int m, int g)
{
    #pragma unroll
    for (int cb = 0; cb < 8; ++cb) {
        float cacc = 0.f;
        bf16x8 bfr[2];
        #pragma unroll
        for (int h = 0; h < 2; ++h) {
            const float* src = centers + (size_t)(cb * 16 + m) * DIMS + h * 32 + g * 8;
            f32x4 c0 = *(const f32x4*)src;
            f32x4 c1 = *(const f32x4*)(src + 4);
            f32x4 s0, s1;
            #pragma unroll
            for (int j = 0; j < 4; ++j) {
                cacc += c0[j] * c0[j] + c1[j] * c1[j];
                s0[j] = -2.0f * c0[j];
                s1[j] = -2.0f * c1[j];
            }
            bfr[h] = pack8(s0, s1);
        }
        cacc += __shfl_xor(cacc, 16);
        cacc += __shfl_xor(cacc, 32);
        if (wid == 0) {
            blds[cb][0][lane] = bfr[0];
            blds[cb][1][lane] = bfr[1];
            if (g == 0) ((float*)cnLDS4)[cb * 16 + m] = cacc;
        }
    }
    __syncthreads();
}

// K1: colsum of q. cn table re-read per tile (opaque index) -> lower VGPR.
__global__ __launch_bounds__(256) void k1_colsum(
        const float* __restrict__ embeds, const float* __restrict__ centers,
        float* __restrict__ colsum_part, int nblocks)
{
    __shared__ bf16x8 blds[8][2][64];
    __shared__ f32x4 cnLDS4[32];
    __shared__ float cl[4 * 128];
    const int tid = threadIdx.x, wid = tid >> 6, lane = tid & 63;
    const int m = lane & 15, g = lane >> 4;

    stage_centers_T(centers, blds, cnLDS4, wid, lane, m, g);

    float csum[8][4];
    #pragma unroll
    for (int cb = 0; cb < 8; ++cb)
        #pragma unroll
        for (int r = 0; r < 4; ++r) csum[cb][r] = 0.f;

    const int gwid = blockIdx.x * 4 + wid;
    const int nw = nblocks * 4;

    int t = gwid;
    f32x4 n0, n1, n2, n3;
    if (t < NTILES) {
        const float* src = embeds + (size_t)(t * 16 + m) * DIMS + g * 8;
        n0 = *(const f32x4*)src;       n1 = *(const f32x4*)(src + 4);
        n2 = *(const f32x4*)(src + 32); n3 = *(const f32x4*)(src + 36);
    }
    for (; t < NTILES; t += nw) {
        const int zr = opaque_zero();
        f32x4 c0 = n0, c1 = n1, c2 = n2, c3 = n3;
        int tn = t + nw;
        if (tn < NTILES) {
            const float* src = embeds + (size_t)(tn * 16 + m) * DIMS + g * 8;
            n0 = *(const f32x4*)src;       n1 = *(const f32x4*)(src + 4);
            n2 = *(const f32x4*)(src + 32); n3 = *(const f32x4*)(src + 36);
        }
        float en = 0.f;
        #pragma unroll
        for (int j = 0; j < 4; ++j)
            en += c0[j] * c0[j] + c1[j] * c1[j] + c2[j] * c2[j] + c3[j] * c3[j];
        bf16x8 a0 = pack8(c0, c1);
        bf16x8 a1 = pack8(c2, c3);
        en += __shfl_xor(en, 16);
        en += __shfl_xor(en, 32);

        f32x4 acc[8];
        #pragma unroll
        for (int cb = 0; cb < 8; ++cb) {
            f32x4 a = {en, en, en, en};          // C = |e|^2; |c|^2 added after
            a = __builtin_amdgcn_mfma_f32_16x16x32_bf16(blds[cb][0][lane], a0, a, 0, 0, 0);
            a = __builtin_amdgcn_mfma_f32_16x16x32_bf16(blds[cb][1][lane], a1, a, 0, 0, 0);
            acc[cb] = a;
        }

        float rsp = 0.f;
        #pragma unroll
        for (int cb = 0; cb < 8; ++cb) {
            f32x4 cn4 = cnLDS4[cb * 4 + g + zr];
            #pragma unroll
            for (int r = 0; r < 4; ++r) {
                float sq = fmaxf(acc[cb][r] + cn4[r], 0.f);
                float dist = frcp(1.0f + sq);
                acc[cb][r] = dist;
                rsp += dist;
            }
        }
        rsp += __shfl_xor(rsp, 16);
        rsp += __shfl_xor(rsp, 32);
        float invR = frcp(rsp);

        #pragma unroll
        for (int cb = 0; cb < 8; ++cb)
            #pragma unroll
            for (int r = 0; r < 4; ++r) csum[cb][r] += acc[cb][r] * invR;
    }

    #pragma unroll
    for (int cb = 0; cb < 8; ++cb)
        #pragma unroll
        for (int r = 0; r < 4; ++r) {
            float v = csum[cb][r];
            v += __shfl_xor(v, 1); v += __shfl_xor(v, 2);
            v += __shfl_xor(v, 4); v += __shfl_xor(v, 8);
            csum[cb][r] = v;
        }
    if (m == 0) {
        #pragma unroll
        for (int cb = 0; cb < 8; ++cb) {
            f32x4 v = {csum[cb][0], csum[cb][1], csum[cb][2], csum[cb][3]};
            *(f32x4*)&cl[wid * 128 + cb * 16 + g * 4] = v;
        }
    }
    __syncthreads();
    if (tid < 128) {
        float s = cl[tid] + cl[128 + tid] + cl[256 + tid] + cl[384 + tid];
        colsum_part[(size_t)tid * nblocks + blockIdx.x] = s;
    }
}

// K1b: 128 blocks, block k reduces contiguous row k -> invS[k], log2S[k]
__global__ __launch_bounds__(256) void k1b_reduce(
        const float* __restrict__ part, float* __restrict__ invS,
        float* __restrict__ lS, int nb)
{
    __shared__ float lds[4];
    const int k = blockIdx.x;
    const int tid = threadIdx.x, wid = tid >> 6, lane = tid & 63;
    float s = 0.f;
    for (int b = tid; b < nb; b += 256) s += part[(size_t)k * nb + b];
    s += __shfl_xor(s, 1);  s += __shfl_xor(s, 2);  s += __shfl_xor(s, 4);
    s += __shfl_xor(s, 8);  s += __shfl_xor(s, 16); s += __shfl_xor(s, 32);
    if (lane == 0) lds[wid] = s;
    __syncthreads();
    if (tid == 0) {
        float tot = lds[0] + lds[1] + lds[2] + lds[3];
        invS[k] = 1.0f / tot;
        lS[k] = __log2f(tot);
    }
}

// K2: recompute sq via transposed MFMA, write q, fused loss (log2 domain).
// cn/is/ls tables re-read per tile via opaque index -> lower VGPR.
__global__ __launch_bounds__(256) void k2_q_loss(
        const float* __restrict__ embeds, const float* __restrict__ centers,
        const float* __restrict__ invS, const float* __restrict__ lS,
        float* __restrict__ q, float* __restrict__ losspart, int nblocks)
{
    __shared__ bf16x8 blds[8][2][64];
    __shared__ f32x4 cnLDS4[32], isLDS4[32], lsLDS4[32];
    __shared__ float lds4[4];
    const int tid = threadIdx.x, wid = tid >> 6, lane = tid & 63;
    const int m = lane & 15, g = lane >> 4;

    if (tid < 128) {
        ((float*)isLDS4)[tid] = invS[tid];
        ((float*)lsLDS4)[tid] = lS[tid];
    }
    stage_centers_T(centers, blds, cnLDS4, wid, lane, m, g);  // has __syncthreads

    float loss = 0.f;
    const int gwid = blockIdx.x * 4 + wid;
    const int nw = nblocks * 4;

    int t = gwid;
    f32x4 n0, n1, n2, n3;
    if (t < NTILES) {
        const float* src = embeds + (size_t)(t * 16 + m) * DIMS + g * 8;
        n0 = *(const f32x4*)src;       n1 = *(const f32x4*)(src + 4);
        n2 = *(const f32x4*)(src + 32); n3 = *(const f32x4*)(src + 36);
    }
    for (; t < NTILES; t += nw) {
        const int zr = opaque_zero();
        f32x4 c0 = n0, c1 = n1, c2 = n2, c3 = n3;
        int tn = t + nw;
        if (tn < NTILES) {
            const float* src = embeds + (size_t)(tn * 16 + m) * DIMS + g * 8;
            n0 = *(const f32x4*)src;       n1 = *(const f32x4*)(src + 4);
            n2 = *(const f32x4*)(src + 32); n3 = *(const f32x4*)(src + 36);
        }
        float en = 0.f;
        #pragma unroll
        for (int j = 0; j < 4; ++j)
            en += c0[j] * c0[j] + c1[j] * c1[j] + c2[j] * c2[j] + c3[j] * c3[j];
        bf16x8 a0 = pack8(c0, c1);
        bf16x8 a1 = pack8(c2, c3);
        en += __shfl_xor(en, 16);
        en += __shfl_xor(en, 32);

        f32x4 acc[8];
        #pragma unroll
        for (int cb = 0; cb < 8; ++cb) {
            f32x4 a = {en, en, en, en};
            a = __builtin_amdgcn_mfma_f32_16x16x32_bf16(blds[cb][0][lane], a0, a, 0, 0, 0);
            a = __builtin_amdgcn_mfma_f32_16x16x32_bf16(blds[cb][1][lane], a1, a, 0, 0, 0);
            acc[cb] = a;
        }

        float rsp = 0.f;
        #pragma unroll
        for (int cb = 0; cb < 8; ++cb) {
            f32x4 cn4 = cnLDS4[cb * 4 + g + zr];
            #pragma unroll
            for (int r = 0; r < 4; ++r) {
                float sq = fmaxf(acc[cb][r] + cn4[r], 0.f);
                float dist = frcp(1.0f + sq);
                acc[cb][r] = dist;
                rsp += dist;
            }
        }
        rsp += __shfl_xor(rsp, 16);
        rsp += __shfl_xor(rsp, 32);
        float invR = frcp(rsp);

        float Wp = 0.f;
        float* qrow = q + (size_t)(t * 16 + m) * KC + g * 4;
        #pragma unroll
        for (int cb = 0; cb < 8; ++cb) {
            f32x4 is4 = isLDS4[cb * 4 + g + zr];
            #pragma unroll
            for (int r = 0; r < 4; ++r) {
                float qv = acc[cb][r] * invR;
                acc[cb][r] = qv;
                qrow[cb * 16 + r] = qv;
                Wp += qv * qv * is4[r];
            }
        }
        Wp += __shfl_xor(Wp, 16);
        Wp += __shfl_xor(Wp, 32);
        float iw = frcp(Wp);
        float lw = __log2f(Wp);

        #pragma unroll
        for (int cb = 0; cb < 8; ++cb) {
            f32x4 is4 = isLDS4[cb * 4 + g + zr];
            f32x4 ls4 = lsLDS4[cb * 4 + g + zr];
            #pragma unroll
            for (int r = 0; r < 4; ++r) {
                float qv = acc[cb][r];
                float w = qv * qv * is4[r];
                loss += w * iw * (__log2f(qv) - ls4[r] - lw);
            }
        }
    }

    loss += __shfl_xor(loss, 1);  loss += __shfl_xor(loss, 2);
    loss += __shfl_xor(loss, 4);  loss += __shfl_xor(loss, 8);
    loss += __shfl_xor(loss, 16); loss += __shfl_xor(loss, 32);
    if (lane == 0) lds4[wid] = loss;
    __syncthreads();
    if (tid == 0) losspart[blockIdx.x] = lds4[0] + lds4[1] + lds4[2] + lds4[3];
}

// K2b: final loss reduce; convert log2 -> ln
__global__ __launch_bounds__(1024) void k2b_final(
        const float* __restrict__ losspart, int nb, float* __restrict__ out)
{
    __shared__ float lds[16];
    const int tid = threadIdx.x;
    float s = 0.f;
    for (int b = tid; b < nb; b += 1024) s += losspart[b];
    s += __shfl_xor(s, 1);  s += __shfl_xor(s, 2);  s += __shfl_xor(s, 4);
    s += __shfl_xor(s, 8);  s += __shfl_xor(s, 16); s += __shfl_xor(s, 32);
    if ((tid & 63) == 0) lds[tid >> 6] = s;
    __syncthreads();
    if (tid == 0) {
        float tot = 0.f;
        #pragma unroll
        for (int i = 0; i < 16; ++i) tot += lds[i];
        out[0] = (float)((double)tot * 0.6931471805599453 /
                         (double)((size_t)NROWS * KC));
    }
}

extern "C" void kernel_launch(void* const* d_in, const int* in_sizes, int n_in,
                              void* d_out, int out_size, void* d_ws, size_t ws_size,
                              hipStream_t stream)
{
    const float* embeds  = (const float*)d_in[0];
    const float* centers = (const float*)d_in[1];
    float* out  = (float*)d_out;
    float* qbuf = out + 1;
    float* ws   = (float*)d_ws;

    // grid oversubscribed vs residency: per-block slices queue+drain, so the
    // grid no longer needs to equal (unknown) resident capacity.
    const int GB1 = 1024, GB2 = 1024;
    float* colsum_part = ws;                          // 128 * GB1 (transposed)
    float* invS  = ws + (size_t)GB1 * 128;            // 128
    float* lS    = invS + 128;                        // 128
    float* lpart = lS + 128;                          // GB2

    hipLaunchKernelGGL(k1_colsum, dim3(GB1), dim3(256), 0, stream,
                       embeds, centers, colsum_part, GB1);
    hipLaunchKernelGGL(k1b_reduce, dim3(128), dim3(256), 0, stream,
                       colsum_part, invS, lS, GB1);
    hipLaunchKernelGGL(k2_q_loss, dim3(GB2), dim3(256), 0, stream,
                       embeds, centers, invS, lS, qbuf, lpart, GB2);
    hipLaunchKernelGGL(k2b_final, dim3(1), dim3(1024), 0, stream,
                       lpart, GB2, out);
}